// Round 14
// baseline (53.508 us; speedup 1.0000x reference)
//
#include <hip/hip_runtime.h>
#include <hip/hip_fp16.h>
#include <math.h>

#define NB    (1 << 20)
#define HH    512
#define WW    1024
#define RANK  16
#define FC    128
#define HW    (HH * WW)
#define TPB   256

#define FP8_SCALE  64.0f
#define FP8_ISCALE 0.015625f

typedef float        f32x16 __attribute__((ext_vector_type(16)));
typedef float        f32x4  __attribute__((ext_vector_type(4)));
typedef float        f32x2  __attribute__((ext_vector_type(2)));
typedef _Float16     f16x8  __attribute__((ext_vector_type(8)));
typedef _Float16     h2     __attribute__((ext_vector_type(2)));
typedef unsigned int uint2v __attribute__((ext_vector_type(2)));

// cvt_pkrtz returns __fp16x2; bit-identical re-type to our h2 (_Float16x2)
__device__ __forceinline__ h2 pkrtz(float a, float b) {
    return __builtin_bit_cast(h2, __builtin_amdgcn_cvt_pkrtz(a, b));
}
// packed f16 relu (elementwise select -> v_pk_max_f16 / 2x v_max_f16)
__device__ __forceinline__ h2 relu2(h2 a) {
    h2 r;
    r[0] = (a[0] > (_Float16)0.0f) ? a[0] : (_Float16)0.0f;
    r[1] = (a[1] > (_Float16)0.0f) ? a[1] : (_Float16)0.0f;
    return r;
}

// Cephes-style atan2, max err ~1e-7 rad
__device__ __forceinline__ float fast_atan2f(float y, float x) {
    float ax = fabsf(x), ay = fabsf(y);
    float mx = fmaxf(ax, ay), mn = fminf(ax, ay);
    float z  = __fdividef(mn, mx);
    if (mx == 0.0f) z = 0.0f;
    bool  red = z > 0.41421356f;
    float zr  = red ? __fdividef(z - 1.0f, z + 1.0f) : z;
    float t2  = zr * zr;
    float p   = (((0.0805374449f * t2 - 0.138776856f) * t2
                 + 0.199777106f) * t2 - 0.333329491f) * t2 * zr + zr;
    if (red)      p += 0.78539816339f;
    if (ay > ax)  p  = 1.57079632679f - p;
    if (x < 0.0f) p  = 3.14159265359f - p;
    return copysignf(p, y);
}
// A&S 4.4.46 7-term acos, max err ~1e-7
__device__ __forceinline__ float fast_acosf(float x) {
    float xa = fabsf(x);
    float p = -0.0012624911f;
    p = p * xa + 0.0066700901f;
    p = p * xa - 0.0170881256f;
    p = p * xa + 0.0308918810f;
    p = p * xa - 0.0501743046f;
    p = p * xa + 0.0889789874f;
    p = p * xa - 0.2145988016f;
    p = p * xa + 1.5707963050f;
    float r = sqrtf(1.0f - xa) * p;
    return x >= 0.0f ? r : 3.14159265359f - r;
}
// softplus via hw exp/log; abs err < 3e-4
__device__ __forceinline__ float softplusf(float a) {
    return fmaxf(a, 0.0f) + __logf(1.0f + __expf(-fabsf(a)));
}

// ---------------------------------------------------------------------------
// Merged pre-pass: (a) planar bg_mat [16][H][W] fp32 -> interleaved fp8-e4m3
// tex [H*W] of uint4 (16 fp8 = 16B per texel), values scaled by 64 into
// e4m3's normal range; nontemporal reads (read-once stream, keep L2 clean).
// (b) block 0 lanes 0-63 build the 12KB per-lane MFMA weight-fragment table.
// ---------------------------------------------------------------------------
__global__ __launch_bounds__(256) void prep_kernel(
    const float* __restrict__ bg,
    const float* __restrict__ W1,      // [16][128] row-major
    const float* __restrict__ W2,      // [128][3] row-major
    uint4* __restrict__ tex8,          // [HW]
    f16x8* __restrict__ table)         // [12][64]
{
    const int base = (blockIdx.x * 256 + threadIdx.x) * 4;   // 4 texels
    f32x4 v[RANK];
    #pragma unroll
    for (int c = 0; c < RANK; ++c)
        v[c] = __builtin_nontemporal_load(
                   (const f32x4*)(bg + (size_t)c * HW + base));

    const float* vf = (const float*)v;   // v[c][j] == vf[4*c + j]
    #pragma unroll
    for (int j = 0; j < 4; ++j) {
        union { unsigned u[4]; uint4 q; } o;
        #pragma unroll
        for (int d = 0; d < 4; ++d) {
            int w = __builtin_amdgcn_cvt_pk_fp8_f32(
                        vf[4 * (4*d + 0) + j] * FP8_SCALE,
                        vf[4 * (4*d + 1) + j] * FP8_SCALE, 0, false);
            w     = __builtin_amdgcn_cvt_pk_fp8_f32(
                        vf[4 * (4*d + 2) + j] * FP8_SCALE,
                        vf[4 * (4*d + 3) + j] * FP8_SCALE, w, true);
            o.u[d] = (unsigned)w;
        }
        tex8[base + j] = o.q;   // cached write: main may hit these lines
    }

    if (blockIdx.x == 0 && threadIdx.x < 64) {
        const int lane = threadIdx.x;
        const int l31  = lane & 31;
        const int q5   = (lane >> 5) & 1;
        #pragma unroll
        for (int jt = 0; jt < 4; ++jt) {
            f16x8 w;
            #pragma unroll
            for (int ii = 0; ii < 8; ++ii)
                w[ii] = (_Float16)W1[(8 * q5 + ii) * FC + 32 * jt + l31];
            table[jt * 64 + lane] = w;
        }
        const bool ok = ((l31 & 3) < 3) && (l31 < 8);
        const int  c3 = l31 & 3;
        #pragma unroll
        for (int kt = 0; kt < 8; ++kt) {
            f16x8 w;
            #pragma unroll
            for (int ii = 0; ii < 8; ++ii) {
                const int n = 16 * kt + 8 * (ii >> 2) + 4 * q5 + (ii & 3);
                w[ii] = ok ? (_Float16)W2[3 * n + c3] : (_Float16)0.0f;
            }
            table[(4 + kt) * 64 + lane] = w;
        }
    }
}

// ---------------------------------------------------------------------------
// Fused render, 1 sample/thread, barrier-free: gather(fp8 tex, ONE dwordx4
// per tap) -> decode+blend in f32 (scale folded into weights) -> pkrtz ->
// permlane32_swap wave transpose -> GEMM1 16->128 (f16 MFMA) -> relu +
// cvt_pkrtz -> GEMM2 128->3 (f16 MFMA, K-permuted so GEMM1 C-layout ==
// GEMM2 B-layout). viewdirs loads + out stores are NONTEMPORAL so the
// streaming 24MB doesn't evict the 8MB texture from L2.
// MODE 0: fp8 tex + frag table; MODE 1: planar f32 fallback.
// ---------------------------------------------------------------------------
template <int MODE>
__global__ __launch_bounds__(TPB, 4) void bg_render_mfma(
    const float* __restrict__ viewdirs,
    const void*  __restrict__ srcv,
    const f16x8* __restrict__ ftab,    // MODE 0 only
    const float* __restrict__ W1,
    const float* __restrict__ W2,
    float* __restrict__ out)
{
    const int tid  = threadIdx.x;
    const int lane = tid & 63;
    const int l31  = tid & 31;
    const int q5   = (tid >> 5) & 1;

    const f32x16 kZero = {0.f,0.f,0.f,0.f,0.f,0.f,0.f,0.f,
                          0.f,0.f,0.f,0.f,0.f,0.f,0.f,0.f};

    const int i = blockIdx.x * TPB + tid;   // this thread's sample

    // ---- equirect unwrap + bilinear setup (matches reference math) ----
    const float dx = __builtin_nontemporal_load(viewdirs + 3 * i + 0);
    const float dy = __builtin_nontemporal_load(viewdirs + 3 * i + 1);
    const float dz = __builtin_nontemporal_load(viewdirs + 3 * i + 2);
    const float INV_PI = 0.31830988618379067154f;
    float phi   = fast_atan2f(dy, dx);
    float theta = fast_acosf(fminf(fmaxf(dz, -1.0f), 1.0f));
    float gx = phi * INV_PI;
    float gy = theta * (2.0f * INV_PI) - 1.0f;

    float ix = (gx + 1.0f) * (0.5f * (float)WW) - 0.5f;
    float iy = (gy + 1.0f) * (0.5f * (float)HH) - 0.5f;
    float x0f = floorf(ix), y0f = floorf(iy);
    float wx1 = ix - x0f, wx0 = 1.0f - wx1;
    float wy1 = iy - y0f, wy0 = 1.0f - wy1;
    int x0 = (int)x0f, y0 = (int)y0f;
    int x1 = x0 + 1,   y1 = y0 + 1;

    float w00 = wx0 * wy0, w10 = wx1 * wy0, w01 = wx0 * wy1, w11 = wx1 * wy1;
    bool vx0 = (x0 >= 0) & (x0 <= WW - 1);
    bool vx1 = (x1 >= 0) & (x1 <= WW - 1);
    bool vy0 = (y0 >= 0) & (y0 <= HH - 1);
    bool vy1 = (y1 >= 0) & (y1 <= HH - 1);
    if (!(vx0 & vy0)) w00 = 0.0f;
    if (!(vx1 & vy0)) w10 = 0.0f;
    if (!(vx0 & vy1)) w01 = 0.0f;
    if (!(vx1 & vy1)) w11 = 0.0f;

    int cx0 = min(max(x0, 0), WW - 1), cx1 = min(max(x1, 0), WW - 1);
    int cy0 = min(max(y0, 0), HH - 1), cy1 = min(max(y1, 0), HH - 1);
    int b00 = cy0 * WW + cx0, b10 = cy0 * WW + cx1;
    int b01 = cy1 * WW + cx0, b11 = cy1 * WW + cx1;

    h2 e[8];
    f16x8 w1f[4], w2f[8];
    if (MODE == 0) {
        const uint4* tex = (const uint4*)srcv;
        // ---- 4 tap loads (one dwordx4 each), issued before any use ----
        uint4 t00 = tex[b00];
        uint4 t10 = tex[b10];
        uint4 t01 = tex[b01];
        uint4 t11 = tex[b11];

        // weight fragments (L1-hot after first waves)
        #pragma unroll
        for (int f = 0; f < 4; ++f) w1f[f] = ftab[f * 64 + lane];
        #pragma unroll
        for (int f = 0; f < 8; ++f) w2f[f] = ftab[(4 + f) * 64 + lane];

        // ---- decode fp8 + blend in f32 (1/64 folded into weights) ----
        float ef[RANK];
        #pragma unroll
        for (int ch = 0; ch < RANK; ++ch) ef[ch] = 0.0f;
        const float s00 = w00 * FP8_ISCALE, s10 = w10 * FP8_ISCALE;
        const float s01 = w01 * FP8_ISCALE, s11 = w11 * FP8_ISCALE;

        auto acc_tap = [&](const uint4& t, float w) {
            const unsigned u[4] = {t.x, t.y, t.z, t.w};
            #pragma unroll
            for (int d = 0; d < 4; ++d) {
                f32x2 lo = __builtin_amdgcn_cvt_pk_f32_fp8((int)u[d], false);
                f32x2 hi = __builtin_amdgcn_cvt_pk_f32_fp8((int)u[d], true);
                ef[4*d + 0] = fmaf(lo.x, w, ef[4*d + 0]);
                ef[4*d + 1] = fmaf(lo.y, w, ef[4*d + 1]);
                ef[4*d + 2] = fmaf(hi.x, w, ef[4*d + 2]);
                ef[4*d + 3] = fmaf(hi.y, w, ef[4*d + 3]);
            }
        };
        acc_tap(t00, s00);
        acc_tap(t10, s10);
        acc_tap(t01, s01);
        acc_tap(t11, s11);

        #pragma unroll
        for (int d = 0; d < 8; ++d)
            e[d] = pkrtz(ef[2 * d], ef[2 * d + 1]);
    } else {
        const float* src = (const float*)srcv;
        float ef[RANK];
        #pragma unroll
        for (int ch = 0; ch < RANK; ++ch) {
            const float* img = src + ch * HW;
            ef[ch] = img[b00] * w00 + img[b10] * w10
                   + img[b01] * w01 + img[b11] * w11;
        }
        #pragma unroll
        for (int d = 0; d < 8; ++d)
            e[d] = pkrtz(ef[2 * d], ef[2 * d + 1]);

        #pragma unroll
        for (int jt = 0; jt < 4; ++jt) {
            f16x8 v;
            #pragma unroll
            for (int ii = 0; ii < 8; ++ii)
                v[ii] = (_Float16)W1[(8 * q5 + ii) * FC + 32 * jt + l31];
            w1f[jt] = v;
        }
        const bool ok = ((l31 & 3) < 3) && (l31 < 8);
        const int  c3 = l31 & 3;
        #pragma unroll
        for (int kt = 0; kt < 8; ++kt) {
            f16x8 v;
            #pragma unroll
            for (int ii = 0; ii < 8; ++ii) {
                const int n = 16 * kt + 8 * (ii >> 2) + 4 * q5 + (ii & 3);
                v[ii] = ok ? (_Float16)W2[3 * n + c3] : (_Float16)0.0f;
            }
            w2f[kt] = v;
        }
    }

    // ---- wave transpose: 4 permlane32_swap build BOTH groups' B-frags ----
    union FragU { f16x8 v; h2 h[4]; unsigned int u[4]; };
    FragU bq0, bq1;
    #pragma unroll
    for (int d = 0; d < 4; ++d) {
        unsigned int lo = __builtin_bit_cast(unsigned int, e[d]);
        unsigned int hi = __builtin_bit_cast(unsigned int, e[d + 4]);
        uint2v r = __builtin_amdgcn_permlane32_swap(lo, hi, false, false);
        bq0.u[d] = r.x;
        bq1.u[d] = r.y;
    }

    // ---- MFMA pipeline, sequential groups (one live f32x16 acc) ----
    float ag[2][3];
    #pragma unroll
    for (int g = 0; g < 2; ++g) {
        const f16x8 bq = (g == 0) ? bq0.v : bq1.v;
        f32x16 acc = kZero;
        #pragma unroll
        for (int jt = 0; jt < 4; ++jt) {
            f32x16 h = __builtin_amdgcn_mfma_f32_32x32x16_f16(w1f[jt], bq, kZero, 0, 0, 0);
            FragU plo, phi_;
            #pragma unroll
            for (int r = 0; r < 4; ++r) {
                plo.h[r]  = relu2(pkrtz(h[2*r],     h[2*r + 1]));
                phi_.h[r] = relu2(pkrtz(h[8 + 2*r], h[8 + 2*r + 1]));
            }
            acc = __builtin_amdgcn_mfma_f32_32x32x16_f16(w2f[2*jt],     plo.v,  acc, 0, 0, 0);
            acc = __builtin_amdgcn_mfma_f32_32x32x16_f16(w2f[2*jt + 1], phi_.v, acc, 0, 0, 0);
        }
        ag[g][0] = acc[0]; ag[g][1] = acc[1]; ag[g][2] = acc[2];
    }

    // ---- epilogue: thread's sample = its lane; q5 picks group ----
    float a0 = q5 ? ag[1][0] : ag[0][0];
    float a1 = q5 ? ag[1][1] : ag[0][1];
    float a2 = q5 ? ag[1][2] : ag[0][2];

    __builtin_nontemporal_store(softplusf(a0), out + 3 * i + 0);
    __builtin_nontemporal_store(softplusf(a1), out + 3 * i + 1);
    __builtin_nontemporal_store(softplusf(a2), out + 3 * i + 2);
}

extern "C" void kernel_launch(void* const* d_in, const int* in_sizes, int n_in,
                              void* d_out, int out_size, void* d_ws, size_t ws_size,
                              hipStream_t stream) {
    const float* viewdirs = (const float*)d_in[0];
    // d_in[1] = roughness: unused by the reference
    const float* bg_mat   = (const float*)d_in[2];
    const float* W1       = (const float*)d_in[3];
    const float* W2       = (const float*)d_in[4];
    float* out            = (float*)d_out;

    const size_t tex_bytes = (size_t)HW * 16;                 // 8 MB fp8 texels
    const size_t tab_bytes = (size_t)12 * 64 * sizeof(f16x8); // 12 KB
    const int nblocks = NB / TPB;   // 4096

    if (ws_size >= tex_bytes + tab_bytes) {
        uint4*  tex8 = (uint4*)d_ws;
        f16x8*  ftab = (f16x8*)((char*)d_ws + tex_bytes);
        prep_kernel<<<dim3(HW / 1024), dim3(256), 0, stream>>>(bg_mat, W1, W2, tex8, ftab);
        bg_render_mfma<0><<<dim3(nblocks), dim3(TPB), 0, stream>>>(
            viewdirs, (const void*)tex8, ftab, W1, W2, out);
    } else {
        bg_render_mfma<1><<<dim3(nblocks), dim3(TPB), 0, stream>>>(
            viewdirs, (const void*)bg_mat, nullptr, W1, W2, out);
    }
}

// Round 15
// 48.309 us; speedup vs baseline: 1.1076x; 1.1076x over previous
//
#include <hip/hip_runtime.h>
#include <hip/hip_fp16.h>
#include <math.h>

#define NB    (1 << 20)
#define HH    512
#define WW    1024
#define RANK  16
#define FC    128
#define HW    (HH * WW)
#define TPB   256

#define FP8_SCALE  64.0f
#define FP8_ISCALE 0.015625f

typedef float        f32x16 __attribute__((ext_vector_type(16)));
typedef float        f32x2  __attribute__((ext_vector_type(2)));
typedef _Float16     f16x8  __attribute__((ext_vector_type(8)));
typedef _Float16     h2     __attribute__((ext_vector_type(2)));
typedef unsigned int uint2v __attribute__((ext_vector_type(2)));

// cvt_pkrtz returns __fp16x2; bit-identical re-type to our h2 (_Float16x2)
__device__ __forceinline__ h2 pkrtz(float a, float b) {
    return __builtin_bit_cast(h2, __builtin_amdgcn_cvt_pkrtz(a, b));
}
// packed f16 relu (elementwise select -> v_pk_max_f16 / 2x v_max_f16)
__device__ __forceinline__ h2 relu2(h2 a) {
    h2 r;
    r[0] = (a[0] > (_Float16)0.0f) ? a[0] : (_Float16)0.0f;
    r[1] = (a[1] > (_Float16)0.0f) ? a[1] : (_Float16)0.0f;
    return r;
}

// Cephes-style atan2, max err ~1e-7 rad
__device__ __forceinline__ float fast_atan2f(float y, float x) {
    float ax = fabsf(x), ay = fabsf(y);
    float mx = fmaxf(ax, ay), mn = fminf(ax, ay);
    float z  = __fdividef(mn, mx);
    if (mx == 0.0f) z = 0.0f;
    bool  red = z > 0.41421356f;
    float zr  = red ? __fdividef(z - 1.0f, z + 1.0f) : z;
    float t2  = zr * zr;
    float p   = (((0.0805374449f * t2 - 0.138776856f) * t2
                 + 0.199777106f) * t2 - 0.333329491f) * t2 * zr + zr;
    if (red)      p += 0.78539816339f;
    if (ay > ax)  p  = 1.57079632679f - p;
    if (x < 0.0f) p  = 3.14159265359f - p;
    return copysignf(p, y);
}
// A&S 4.4.46 7-term acos, max err ~1e-7
__device__ __forceinline__ float fast_acosf(float x) {
    float xa = fabsf(x);
    float p = -0.0012624911f;
    p = p * xa + 0.0066700901f;
    p = p * xa - 0.0170881256f;
    p = p * xa + 0.0308918810f;
    p = p * xa - 0.0501743046f;
    p = p * xa + 0.0889789874f;
    p = p * xa - 0.2145988016f;
    p = p * xa + 1.5707963050f;
    float r = sqrtf(1.0f - xa) * p;
    return x >= 0.0f ? r : 3.14159265359f - r;
}
// softplus via hw exp/log; abs err < 3e-4
__device__ __forceinline__ float softplusf(float a) {
    return fmaxf(a, 0.0f) + __logf(1.0f + __expf(-fabsf(a)));
}

// ---------------------------------------------------------------------------
// Merged pre-pass: (a) planar bg_mat [16][H][W] fp32 -> interleaved fp8-e4m3
// tex [H*W] of uint4 (16 fp8 = 16B per texel), values scaled by 64 into
// e4m3's normal range; (b) block 0 lanes 0-63 build the 12KB per-lane MFMA
// weight-fragment table.
// ---------------------------------------------------------------------------
__global__ __launch_bounds__(256) void prep_kernel(
    const float* __restrict__ bg,
    const float* __restrict__ W1,      // [16][128] row-major
    const float* __restrict__ W2,      // [128][3] row-major
    uint4* __restrict__ tex8,          // [HW]
    f16x8* __restrict__ table)         // [12][64]
{
    const int base = (blockIdx.x * 256 + threadIdx.x) * 2;   // 2 texels
    float2 v[RANK];
    #pragma unroll
    for (int c = 0; c < RANK; ++c)
        v[c] = *(const float2*)(bg + (size_t)c * HW + base);

    #pragma unroll
    for (int j = 0; j < 2; ++j) {
        float c[RANK];
        #pragma unroll
        for (int ch = 0; ch < RANK; ++ch)
            c[ch] = (j ? v[ch].y : v[ch].x) * FP8_SCALE;
        union { unsigned u[4]; uint4 q; } o;
        #pragma unroll
        for (int d = 0; d < 4; ++d) {
            int w = __builtin_amdgcn_cvt_pk_fp8_f32(c[4*d + 0], c[4*d + 1], 0, false);
            w     = __builtin_amdgcn_cvt_pk_fp8_f32(c[4*d + 2], c[4*d + 3], w, true);
            o.u[d] = (unsigned)w;
        }
        tex8[base + j] = o.q;
    }

    if (blockIdx.x == 0 && threadIdx.x < 64) {
        const int lane = threadIdx.x;
        const int l31  = lane & 31;
        const int q5   = (lane >> 5) & 1;
        #pragma unroll
        for (int jt = 0; jt < 4; ++jt) {
            f16x8 w;
            #pragma unroll
            for (int ii = 0; ii < 8; ++ii)
                w[ii] = (_Float16)W1[(8 * q5 + ii) * FC + 32 * jt + l31];
            table[jt * 64 + lane] = w;
        }
        const bool ok = ((l31 & 3) < 3) && (l31 < 8);
        const int  c3 = l31 & 3;
        #pragma unroll
        for (int kt = 0; kt < 8; ++kt) {
            f16x8 w;
            #pragma unroll
            for (int ii = 0; ii < 8; ++ii) {
                const int n = 16 * kt + 8 * (ii >> 2) + 4 * q5 + (ii & 3);
                w[ii] = ok ? (_Float16)W2[3 * n + c3] : (_Float16)0.0f;
            }
            table[(4 + kt) * 64 + lane] = w;
        }
    }
}

// ---------------------------------------------------------------------------
// Fused render, 1 sample/thread, barrier-free: gather(fp8 tex, ONE dwordx4
// per tap) -> decode+blend in f32 (scale folded into weights) -> pkrtz ->
// permlane32_swap wave transpose -> GEMM1 16->128 (f16 MFMA) -> relu +
// cvt_pkrtz -> GEMM2 128->3 (f16 MFMA, K-permuted so GEMM1 C-layout ==
// GEMM2 B-layout). MODE 0: fp8 tex + frag table; MODE 1: planar f32.
// ---------------------------------------------------------------------------
template <int MODE>
__global__ __launch_bounds__(TPB, 4) void bg_render_mfma(
    const float* __restrict__ viewdirs,
    const void*  __restrict__ srcv,
    const f16x8* __restrict__ ftab,    // MODE 0 only
    const float* __restrict__ W1,
    const float* __restrict__ W2,
    float* __restrict__ out)
{
    const int tid  = threadIdx.x;
    const int lane = tid & 63;
    const int l31  = tid & 31;
    const int q5   = (tid >> 5) & 1;

    const f32x16 kZero = {0.f,0.f,0.f,0.f,0.f,0.f,0.f,0.f,
                          0.f,0.f,0.f,0.f,0.f,0.f,0.f,0.f};

    const int i = blockIdx.x * TPB + tid;   // this thread's sample

    // ---- equirect unwrap + bilinear setup (matches reference math) ----
    const float dx = viewdirs[3 * i + 0];
    const float dy = viewdirs[3 * i + 1];
    const float dz = viewdirs[3 * i + 2];
    const float INV_PI = 0.31830988618379067154f;
    float phi   = fast_atan2f(dy, dx);
    float theta = fast_acosf(fminf(fmaxf(dz, -1.0f), 1.0f));
    float gx = phi * INV_PI;
    float gy = theta * (2.0f * INV_PI) - 1.0f;

    float ix = (gx + 1.0f) * (0.5f * (float)WW) - 0.5f;
    float iy = (gy + 1.0f) * (0.5f * (float)HH) - 0.5f;
    float x0f = floorf(ix), y0f = floorf(iy);
    float wx1 = ix - x0f, wx0 = 1.0f - wx1;
    float wy1 = iy - y0f, wy0 = 1.0f - wy1;
    int x0 = (int)x0f, y0 = (int)y0f;
    int x1 = x0 + 1,   y1 = y0 + 1;

    float w00 = wx0 * wy0, w10 = wx1 * wy0, w01 = wx0 * wy1, w11 = wx1 * wy1;
    bool vx0 = (x0 >= 0) & (x0 <= WW - 1);
    bool vx1 = (x1 >= 0) & (x1 <= WW - 1);
    bool vy0 = (y0 >= 0) & (y0 <= HH - 1);
    bool vy1 = (y1 >= 0) & (y1 <= HH - 1);
    if (!(vx0 & vy0)) w00 = 0.0f;
    if (!(vx1 & vy0)) w10 = 0.0f;
    if (!(vx0 & vy1)) w01 = 0.0f;
    if (!(vx1 & vy1)) w11 = 0.0f;

    int cx0 = min(max(x0, 0), WW - 1), cx1 = min(max(x1, 0), WW - 1);
    int cy0 = min(max(y0, 0), HH - 1), cy1 = min(max(y1, 0), HH - 1);
    int b00 = cy0 * WW + cx0, b10 = cy0 * WW + cx1;
    int b01 = cy1 * WW + cx0, b11 = cy1 * WW + cx1;

    h2 e[8];
    f16x8 w1f[4], w2f[8];
    if (MODE == 0) {
        const uint4* tex = (const uint4*)srcv;
        // ---- 4 tap loads (one dwordx4 each), issued before any use ----
        uint4 t00 = tex[b00];
        uint4 t10 = tex[b10];
        uint4 t01 = tex[b01];
        uint4 t11 = tex[b11];

        // weight fragments (L1-hot after first waves)
        #pragma unroll
        for (int f = 0; f < 4; ++f) w1f[f] = ftab[f * 64 + lane];
        #pragma unroll
        for (int f = 0; f < 8; ++f) w2f[f] = ftab[(4 + f) * 64 + lane];

        // ---- decode fp8 + blend in f32 (1/64 folded into weights) ----
        float ef[RANK];
        #pragma unroll
        for (int ch = 0; ch < RANK; ++ch) ef[ch] = 0.0f;
        const float s00 = w00 * FP8_ISCALE, s10 = w10 * FP8_ISCALE;
        const float s01 = w01 * FP8_ISCALE, s11 = w11 * FP8_ISCALE;

        auto acc_tap = [&](const uint4& t, float w) {
            const unsigned u[4] = {t.x, t.y, t.z, t.w};
            #pragma unroll
            for (int d = 0; d < 4; ++d) {
                f32x2 lo = __builtin_amdgcn_cvt_pk_f32_fp8((int)u[d], false);
                f32x2 hi = __builtin_amdgcn_cvt_pk_f32_fp8((int)u[d], true);
                ef[4*d + 0] = fmaf(lo.x, w, ef[4*d + 0]);
                ef[4*d + 1] = fmaf(lo.y, w, ef[4*d + 1]);
                ef[4*d + 2] = fmaf(hi.x, w, ef[4*d + 2]);
                ef[4*d + 3] = fmaf(hi.y, w, ef[4*d + 3]);
            }
        };
        acc_tap(t00, s00);
        acc_tap(t10, s10);
        acc_tap(t01, s01);
        acc_tap(t11, s11);

        #pragma unroll
        for (int d = 0; d < 8; ++d)
            e[d] = pkrtz(ef[2 * d], ef[2 * d + 1]);
    } else {
        const float* src = (const float*)srcv;
        float ef[RANK];
        #pragma unroll
        for (int ch = 0; ch < RANK; ++ch) {
            const float* img = src + ch * HW;
            ef[ch] = img[b00] * w00 + img[b10] * w10
                   + img[b01] * w01 + img[b11] * w11;
        }
        #pragma unroll
        for (int d = 0; d < 8; ++d)
            e[d] = pkrtz(ef[2 * d], ef[2 * d + 1]);

        #pragma unroll
        for (int jt = 0; jt < 4; ++jt) {
            f16x8 v;
            #pragma unroll
            for (int ii = 0; ii < 8; ++ii)
                v[ii] = (_Float16)W1[(8 * q5 + ii) * FC + 32 * jt + l31];
            w1f[jt] = v;
        }
        const bool ok = ((l31 & 3) < 3) && (l31 < 8);
        const int  c3 = l31 & 3;
        #pragma unroll
        for (int kt = 0; kt < 8; ++kt) {
            f16x8 v;
            #pragma unroll
            for (int ii = 0; ii < 8; ++ii) {
                const int n = 16 * kt + 8 * (ii >> 2) + 4 * q5 + (ii & 3);
                v[ii] = ok ? (_Float16)W2[3 * n + c3] : (_Float16)0.0f;
            }
            w2f[kt] = v;
        }
    }

    // ---- wave transpose: 4 permlane32_swap build BOTH groups' B-frags ----
    union FragU { f16x8 v; h2 h[4]; unsigned int u[4]; };
    FragU bq0, bq1;
    #pragma unroll
    for (int d = 0; d < 4; ++d) {
        unsigned int lo = __builtin_bit_cast(unsigned int, e[d]);
        unsigned int hi = __builtin_bit_cast(unsigned int, e[d + 4]);
        uint2v r = __builtin_amdgcn_permlane32_swap(lo, hi, false, false);
        bq0.u[d] = r.x;
        bq1.u[d] = r.y;
    }

    // ---- MFMA pipeline, sequential groups (one live f32x16 acc) ----
    float ag[2][3];
    #pragma unroll
    for (int g = 0; g < 2; ++g) {
        const f16x8 bq = (g == 0) ? bq0.v : bq1.v;
        f32x16 acc = kZero;
        #pragma unroll
        for (int jt = 0; jt < 4; ++jt) {
            f32x16 h = __builtin_amdgcn_mfma_f32_32x32x16_f16(w1f[jt], bq, kZero, 0, 0, 0);
            FragU plo, phi_;
            #pragma unroll
            for (int r = 0; r < 4; ++r) {
                plo.h[r]  = relu2(pkrtz(h[2*r],     h[2*r + 1]));
                phi_.h[r] = relu2(pkrtz(h[8 + 2*r], h[8 + 2*r + 1]));
            }
            acc = __builtin_amdgcn_mfma_f32_32x32x16_f16(w2f[2*jt],     plo.v,  acc, 0, 0, 0);
            acc = __builtin_amdgcn_mfma_f32_32x32x16_f16(w2f[2*jt + 1], phi_.v, acc, 0, 0, 0);
        }
        ag[g][0] = acc[0]; ag[g][1] = acc[1]; ag[g][2] = acc[2];
    }

    // ---- epilogue: thread's sample = its lane; q5 picks group ----
    float a0 = q5 ? ag[1][0] : ag[0][0];
    float a1 = q5 ? ag[1][1] : ag[0][1];
    float a2 = q5 ? ag[1][2] : ag[0][2];

    out[3 * i + 0] = softplusf(a0);
    out[3 * i + 1] = softplusf(a1);
    out[3 * i + 2] = softplusf(a2);
}

extern "C" void kernel_launch(void* const* d_in, const int* in_sizes, int n_in,
                              void* d_out, int out_size, void* d_ws, size_t ws_size,
                              hipStream_t stream) {
    const float* viewdirs = (const float*)d_in[0];
    // d_in[1] = roughness: unused by the reference
    const float* bg_mat   = (const float*)d_in[2];
    const float* W1       = (const float*)d_in[3];
    const float* W2       = (const float*)d_in[4];
    float* out            = (float*)d_out;

    const size_t tex_bytes = (size_t)HW * 16;                 // 8 MB fp8 texels
    const size_t tab_bytes = (size_t)12 * 64 * sizeof(f16x8); // 12 KB
    const int nblocks = NB / TPB;   // 4096

    if (ws_size >= tex_bytes + tab_bytes) {
        uint4*  tex8 = (uint4*)d_ws;
        f16x8*  ftab = (f16x8*)((char*)d_ws + tex_bytes);
        prep_kernel<<<dim3(HW / 512), dim3(256), 0, stream>>>(bg_mat, W1, W2, tex8, ftab);
        bg_render_mfma<0><<<dim3(nblocks), dim3(TPB), 0, stream>>>(
            viewdirs, (const void*)tex8, ftab, W1, W2, out);
    } else {
        bg_render_mfma<1><<<dim3(nblocks), dim3(TPB), 0, stream>>>(
            viewdirs, (const void*)bg_mat, nullptr, W1, W2, out);
    }
}